// Round 6
// baseline (165.571 us; speedup 1.0000x reference)
//
#include <hip/hip_runtime.h>

#define BB 64
#define NN 512
#define DD 128
#define TT 8
#define NEG_SLOPE 0.2f

typedef float f32x4 __attribute__((ext_vector_type(4)));
typedef int i32x4 __attribute__((ext_vector_type(4)));

// ---------------------------------------------------------------------------
// Kernel 1: projections (outer-product layout).
// Lane owns (t = lane&7, d-chunk = lane>>3, 16 d's). a slice (16 coeffs x 2
// halves) lives in 32 regs. Per row: 4 f32x4 x-loads (8 unique 16B segs,
// dup-coalesced) + 16 FMA + 3 shfl_xor(8,16,32) -> every lane holds s[r][t].
// 8 rows per wave; store redistributed via cndmask chain so lane l stores
// row (l>>3), t (l&7): s_src contiguous 256B, s_dstT 8x32B segments.
// ---------------------------------------------------------------------------
__global__ __launch_bounds__(256) void precompute_scores(
    const float* __restrict__ src, const float* __restrict__ dst,
    const float* __restrict__ a, float* __restrict__ s_src,
    float* __restrict__ s_dstT) {
  const int tid = threadIdx.x;
  const int wave = tid >> 6, lane = tid & 63;
  const int t = lane & 7, dc = lane >> 3;
  const int d0 = dc * 16;
  const int r0 = (blockIdx.x * 4 + wave) * 8;  // 8 rows per wave

  f32x4 as[4], ad[4];
#pragma unroll
  for (int i = 0; i < 4; ++i) {
    as[i] = *(const f32x4*)(a + t * 2 * DD + d0 + 4 * i);
    ad[i] = *(const f32x4*)(a + t * 2 * DD + DD + d0 + 4 * i);
  }

  float ps[8], pd[8];
#pragma unroll
  for (int ri = 0; ri < 8; ++ri) {
    const long r = r0 + ri;
    float p = 0.f, q = 0.f;
#pragma unroll
    for (int i = 0; i < 4; ++i) {
      const f32x4 x = *(const f32x4*)(src + r * DD + d0 + 4 * i);
      p += x.x * as[i].x + x.y * as[i].y + x.z * as[i].z + x.w * as[i].w;
      const f32x4 y = *(const f32x4*)(dst + r * DD + d0 + 4 * i);
      q += y.x * ad[i].x + y.y * ad[i].y + y.z * ad[i].z + y.w * ad[i].w;
    }
    // reduce over d-chunks (lane bits 3,4,5); all lanes end with full sum
    p += __shfl_xor(p, 8, 64);
    p += __shfl_xor(p, 16, 64);
    p += __shfl_xor(p, 32, 64);
    q += __shfl_xor(q, 8, 64);
    q += __shfl_xor(q, 16, 64);
    q += __shfl_xor(q, 32, 64);
    ps[ri] = p;
    pd[ri] = q;
  }

  // lane l stores row r0 + (l>>3) = r0 + dc, feature t
  float vs = ps[0], vd = pd[0];
#pragma unroll
  for (int ri = 1; ri < 8; ++ri) {
    vs = dc == ri ? ps[ri] : vs;
    vd = dc == ri ? pd[ri] : vd;
  }
  const int rr = r0 + dc;
  s_src[(long)rr * TT + t] = vs;  // addr = r0*8 + lane: contiguous
  const int b = rr >> 9, n = rr & 511;
  s_dstT[((long)b * TT + t) * NN + n] = vd;  // 8 x 32B segments
}

// ---------------------------------------------------------------------------
// Kernel 2: out[b,i,j] = leakyrelu( (e>=0) ? s_src[b,i,e] + s_dst[b,j,e] : 0 )
// Block = (b, 32-row i-tile), 512 threads (8 waves; 4 blocks/CU -> 32
// waves/CU). s_dstT[b] staged into LDS as [j][t] padded to 9 floats:
// gather bank = (4*lane + 9m + k)&31, k random -> ~2-way (free).
// ssc gather: r wave-uniform, 8 distinct banks, broadcast -> conflict-free.
// Edges int4 loads / f32x4 nontemporal stores (16 B/lane).
// ---------------------------------------------------------------------------
__global__ __launch_bounds__(512) void edge_attention(
    const int* __restrict__ edges, const float* __restrict__ s_src,
    const float* __restrict__ s_dstT, float* __restrict__ out) {
  __shared__ float sdt[NN * 9];    // [j][t] pad 9 -> 18 KB
  __shared__ float ssc[32 * TT];   // [local row][t] 1 KB

  const int tid = threadIdx.x;
  const int b = blockIdx.x >> 4;         // 16 i-tiles per b
  const int i0 = (blockIdx.x & 15) * 32;

  // stage s_dstT[b] (t-major source) into [j][t] pad-9: coalesced global,
  // LDS write bank = (9*tid+q)&31 -> spread (9 odd)
  const float* __restrict__ g_sdt = s_dstT + (long)b * NN * TT;
#pragma unroll
  for (int q = 0; q < TT; ++q) sdt[tid * 9 + q] = g_sdt[q * NN + tid];

  // stage 32 rows of s_src: 256 floats = 64 f32x4
  if (tid < 64) {
    ((f32x4*)ssc)[tid] =
        ((const f32x4*)(s_src + ((long)b * NN + i0) * TT))[tid];
  }
  __syncthreads();

  const int rsub = tid >> 7;         // 0..3: row subgroup
  const int j0 = (tid & 127) * 4;

#pragma unroll 4
  for (int it = 0; it < 8; ++it) {
    const int r = it * 4 + rsub;                   // local row 0..31
    const long base = ((long)(b * NN + i0 + r)) * NN + j0;
    const i32x4 e4 = *(const i32x4*)(edges + base);
    const float* __restrict__ sr = ssc + r * TT;

    const int ee[4] = {e4.x, e4.y, e4.z, e4.w};
    float oo[4];
#pragma unroll
    for (int m = 0; m < 4; ++m) {
      const int e = ee[m];
      const int k = e < 0 ? 0 : e;  // e>=0 is already < T
      const float g = sr[k] + sdt[(j0 + m) * 9 + k];
      const float v = e < 0 ? 0.0f : g;
      oo[m] = v >= 0.0f ? v : NEG_SLOPE * v;
    }
    const f32x4 o = {oo[0], oo[1], oo[2], oo[3]};
    __builtin_nontemporal_store(o, (f32x4*)(out + base));
  }
}

// ---------------------------------------------------------------------------
extern "C" void kernel_launch(void* const* d_in, const int* in_sizes, int n_in,
                              void* d_out, int out_size, void* d_ws, size_t ws_size,
                              hipStream_t stream) {
  const float* src = (const float*)d_in[0];
  const float* dst = (const float*)d_in[1];
  const int* edges = (const int*)d_in[2];
  const float* a = (const float*)d_in[3];
  float* out = (float*)d_out;

  float* s_src = (float*)d_ws;                       // [B*N, T]   1 MiB
  float* s_dstT = s_src + (long)BB * NN * TT;        // [B, T, N]  1 MiB

  // Kernel 1: 32768 row-indices, 8 per wave, 4 waves/block -> 1024 blocks
  precompute_scores<<<1024, 256, 0, stream>>>(src, dst, a, s_src, s_dstT);

  // Kernel 2: (b, i-tile of 32) per block, 512 threads
  edge_attention<<<BB * 16, 512, 0, stream>>>(edges, s_src, s_dstT, out);
}

// Round 8
// 162.988 us; speedup vs baseline: 1.0158x; 1.0158x over previous
//
#include <hip/hip_runtime.h>

#define BB 64
#define NN 512
#define DD 128
#define TT 8
#define NEG_SLOPE 0.2f

typedef float f32x4 __attribute__((ext_vector_type(4)));
typedef int i32x4 __attribute__((ext_vector_type(4)));

// ---------------------------------------------------------------------------
// Kernel 1: projections (outer-product layout) — unchanged from R6.
// Lane owns (t = lane&7, d-chunk = lane>>3, 16 d's). Per row: 4 f32x4 loads
// x2 + 32 FMA + 6 shfl_xor(8,16,32). 8 rows/wave; redistributed stores.
// ---------------------------------------------------------------------------
__global__ __launch_bounds__(256) void precompute_scores(
    const float* __restrict__ src, const float* __restrict__ dst,
    const float* __restrict__ a, float* __restrict__ s_src,
    float* __restrict__ s_dstT) {
  const int tid = threadIdx.x;
  const int wave = tid >> 6, lane = tid & 63;
  const int t = lane & 7, dc = lane >> 3;
  const int d0 = dc * 16;
  const int r0 = (blockIdx.x * 4 + wave) * 8;  // 8 rows per wave

  f32x4 as[4], ad[4];
#pragma unroll
  for (int i = 0; i < 4; ++i) {
    as[i] = *(const f32x4*)(a + t * 2 * DD + d0 + 4 * i);
    ad[i] = *(const f32x4*)(a + t * 2 * DD + DD + d0 + 4 * i);
  }

  float ps[8], pd[8];
#pragma unroll
  for (int ri = 0; ri < 8; ++ri) {
    const long r = r0 + ri;
    float p = 0.f, q = 0.f;
#pragma unroll
    for (int i = 0; i < 4; ++i) {
      const f32x4 x = *(const f32x4*)(src + r * DD + d0 + 4 * i);
      p += x.x * as[i].x + x.y * as[i].y + x.z * as[i].z + x.w * as[i].w;
      const f32x4 y = *(const f32x4*)(dst + r * DD + d0 + 4 * i);
      q += y.x * ad[i].x + y.y * ad[i].y + y.z * ad[i].z + y.w * ad[i].w;
    }
    p += __shfl_xor(p, 8, 64);
    p += __shfl_xor(p, 16, 64);
    p += __shfl_xor(p, 32, 64);
    q += __shfl_xor(q, 8, 64);
    q += __shfl_xor(q, 16, 64);
    q += __shfl_xor(q, 32, 64);
    ps[ri] = p;
    pd[ri] = q;
  }

  float vs = ps[0], vd = pd[0];
#pragma unroll
  for (int ri = 1; ri < 8; ++ri) {
    vs = dc == ri ? ps[ri] : vs;
    vd = dc == ri ? pd[ri] : vd;
  }
  const int rr = r0 + dc;
  s_src[(long)rr * TT + t] = vs;  // contiguous per wave
  const int b = rr >> 9, n = rr & 511;
  s_dstT[((long)b * TT + t) * NN + n] = vd;  // [b][t][n], 8 x 32B segments
}

// ---------------------------------------------------------------------------
// Kernel 2: out[b,i,j] = leakyrelu( (e>=0) ? s_src[b,i,e] + s_dst[b,j,e] : 0 )
// 512 threads, block = (b, 32-row i-tile). BATCHED MLP version:
//   - all 8 edge int4 loads issued up front (2 reg groups of 4)
//   - per group: 16 sdt gathers + 16 sr multicast reads issued before any
//     consumption (one batched lgkm drain instead of 8 serial ones)
//   - then 4 masked/leaky f32x4 nt stores.
// sr gather ssc[r*8+k]: r wave-uniform, k in 0..7 -> 8 consecutive words =
// 8 distinct banks + broadcasts: conflict-free. sdt pad-9: ~2.5-way.
// ---------------------------------------------------------------------------
__global__ __launch_bounds__(512) void edge_attention(
    const int* __restrict__ edges, const float* __restrict__ s_src,
    const float* __restrict__ s_dstT, float* __restrict__ out) {
  __shared__ float sdt[NN * 9];    // [j][t] pad 9 -> 18 KB
  __shared__ float ssc[32 * TT];   // [local row][t] 1 KB

  const int tid = threadIdx.x;
  const int b = blockIdx.x >> 4;         // 16 i-tiles per b
  const int i0 = (blockIdx.x & 15) * 32;

  // stage s_dstT[b] ([t][n] source) into [j][t] pad-9
  const float* __restrict__ g_sdt = s_dstT + (long)b * NN * TT;
#pragma unroll
  for (int q = 0; q < TT; ++q) sdt[tid * 9 + q] = g_sdt[q * NN + tid];

  // stage 32 rows of s_src
  if (tid < 64) {
    ((f32x4*)ssc)[tid] =
        ((const f32x4*)(s_src + ((long)b * NN + i0) * TT))[tid];
  }
  __syncthreads();

  const int rsub = tid >> 7;          // 0..3
  const int j0 = (tid & 127) * 4;
  // thread's row for iteration it is r = it*4 + rsub; address step = 4*NN
  const long base0 = ((long)(b * NN + i0 + rsub)) * NN + j0;

  // ---- issue ALL 8 edge loads up front (8 KB/lane-group in flight) ----
  i32x4 ea[4], eb[4];
#pragma unroll
  for (int i = 0; i < 4; ++i)
    ea[i] = *(const i32x4*)(edges + base0 + (long)(i * 4) * NN);
#pragma unroll
  for (int i = 0; i < 4; ++i)
    eb[i] = *(const i32x4*)(edges + base0 + (long)(16 + i * 4) * NN);

  // ---- group A: rows rsub + {0,4,8,12} ----
  {
    float va[4][4];
#pragma unroll
    for (int i = 0; i < 4; ++i) {
      const int r = i * 4 + rsub;
      const int es[4] = {ea[i].x, ea[i].y, ea[i].z, ea[i].w};
#pragma unroll
      for (int m = 0; m < 4; ++m) {
        const int k = es[m] < 0 ? 0 : es[m];   // v_max_i32
        va[i][m] = ssc[r * TT + k] + sdt[(j0 + m) * 9 + k];
      }
    }
#pragma unroll
    for (int i = 0; i < 4; ++i) {
      const int es[4] = {ea[i].x, ea[i].y, ea[i].z, ea[i].w};
      float oo[4];
#pragma unroll
      for (int m = 0; m < 4; ++m) {
        float w = fmaxf(va[i][m], NEG_SLOPE * va[i][m]);  // leaky
        oo[m] = es[m] < 0 ? 0.0f : w;                      // edge mask
      }
      const f32x4 o = {oo[0], oo[1], oo[2], oo[3]};
      __builtin_nontemporal_store(o, (f32x4*)(out + base0 + (long)(i * 4) * NN));
    }
  }

  // ---- group B: rows rsub + {16,20,24,28} ----
  {
    float vb[4][4];
#pragma unroll
    for (int i = 0; i < 4; ++i) {
      const int r = 16 + i * 4 + rsub;
      const int es[4] = {eb[i].x, eb[i].y, eb[i].z, eb[i].w};
#pragma unroll
      for (int m = 0; m < 4; ++m) {
        const int k = es[m] < 0 ? 0 : es[m];
        vb[i][m] = ssc[r * TT + k] + sdt[(j0 + m) * 9 + k];
      }
    }
#pragma unroll
    for (int i = 0; i < 4; ++i) {
      const int es[4] = {eb[i].x, eb[i].y, eb[i].z, eb[i].w};
      float oo[4];
#pragma unroll
      for (int m = 0; m < 4; ++m) {
        float w = fmaxf(vb[i][m], NEG_SLOPE * vb[i][m]);
        oo[m] = es[m] < 0 ? 0.0f : w;
      }
      const f32x4 o = {oo[0], oo[1], oo[2], oo[3]};
      __builtin_nontemporal_store(
          o, (f32x4*)(out + base0 + (long)(16 + i * 4) * NN));
    }
  }
}

// ---------------------------------------------------------------------------
extern "C" void kernel_launch(void* const* d_in, const int* in_sizes, int n_in,
                              void* d_out, int out_size, void* d_ws, size_t ws_size,
                              hipStream_t stream) {
  const float* src = (const float*)d_in[0];
  const float* dst = (const float*)d_in[1];
  const int* edges = (const int*)d_in[2];
  const float* a = (const float*)d_in[3];
  float* out = (float*)d_out;

  float* s_src = (float*)d_ws;                       // [B*N, T]   1 MiB
  float* s_dstT = s_src + (long)BB * NN * TT;        // [B, T, N]  1 MiB

  precompute_scores<<<1024, 256, 0, stream>>>(src, dst, a, s_src, s_dstT);
  edge_attention<<<BB * 16, 512, 0, stream>>>(edges, s_src, s_dstT, out);
}

// Round 13
// 157.992 us; speedup vs baseline: 1.0480x; 1.0316x over previous
//
#include <hip/hip_runtime.h>

#define BB 64
#define NN 512
#define DD 128
#define TT 8
#define NEG_SLOPE 0.2f

typedef float f32x4 __attribute__((ext_vector_type(4)));
typedef int i32x4 __attribute__((ext_vector_type(4)));

// ---------------------------------------------------------------------------
// Kernel 1: projections (outer-product layout) — unchanged.
// ---------------------------------------------------------------------------
__global__ __launch_bounds__(256) void precompute_scores(
    const float* __restrict__ src, const float* __restrict__ dst,
    const float* __restrict__ a, float* __restrict__ s_src,
    float* __restrict__ s_dstT) {
  const int tid = threadIdx.x;
  const int wave = tid >> 6, lane = tid & 63;
  const int t = lane & 7, dc = lane >> 3;
  const int d0 = dc * 16;
  const int r0 = (blockIdx.x * 4 + wave) * 8;  // 8 rows per wave

  f32x4 as[4], ad[4];
#pragma unroll
  for (int i = 0; i < 4; ++i) {
    as[i] = *(const f32x4*)(a + t * 2 * DD + d0 + 4 * i);
    ad[i] = *(const f32x4*)(a + t * 2 * DD + DD + d0 + 4 * i);
  }

  float ps[8], pd[8];
#pragma unroll
  for (int ri = 0; ri < 8; ++ri) {
    const long r = r0 + ri;
    float p = 0.f, q = 0.f;
#pragma unroll
    for (int i = 0; i < 4; ++i) {
      const f32x4 x = *(const f32x4*)(src + r * DD + d0 + 4 * i);
      p += x.x * as[i].x + x.y * as[i].y + x.z * as[i].z + x.w * as[i].w;
      const f32x4 y = *(const f32x4*)(dst + r * DD + d0 + 4 * i);
      q += y.x * ad[i].x + y.y * ad[i].y + y.z * ad[i].z + y.w * ad[i].w;
    }
    p += __shfl_xor(p, 8, 64);
    p += __shfl_xor(p, 16, 64);
    p += __shfl_xor(p, 32, 64);
    q += __shfl_xor(q, 8, 64);
    q += __shfl_xor(q, 16, 64);
    q += __shfl_xor(q, 32, 64);
    ps[ri] = p;
    pd[ri] = q;
  }

  float vs = ps[0], vd = pd[0];
#pragma unroll
  for (int ri = 1; ri < 8; ++ri) {
    vs = dc == ri ? ps[ri] : vs;
    vd = dc == ri ? pd[ri] : vd;
  }
  const int rr = r0 + dc;
  s_src[(long)rr * TT + t] = vs;  // contiguous per wave
  const int b = rr >> 9, n = rr & 511;
  s_dstT[((long)b * TT + t) * NN + n] = vd;  // [b][t][n], 8 x 32B segments
}

// ---------------------------------------------------------------------------
// Kernel 2 (register-select version):
//   out[b,i,j] = leakyrelu( (e>=0) ? s_src[b,i,e] + s_dst[b,j,e] : 0 )
// Block = 256 threads covering (b, 16-row i-tile, 256-wide j-half); 4096
// blocks. Each thread holds s_dstT[b][t][j0..j0+3] for ALL t in 32 VGPRs
// (8 coalesced f32x4 loads, L2-resident slice); gather = 7-cndmask binary
// tree on k's bits. No sdt LDS, no nt stores, tiny LDS (ssc 512 B,
// wave-uniform row -> broadcast, conflict-free).
// ---------------------------------------------------------------------------
__global__ __launch_bounds__(256) void edge_attention(
    const int* __restrict__ edges, const float* __restrict__ s_src,
    const float* __restrict__ s_dstT, float* __restrict__ out) {
  __shared__ float ssc[16 * TT];  // [local row][t] 512 B

  const int tid = threadIdx.x;
  const int wave = tid >> 6, lane = tid & 63;
  const int bid = blockIdx.x;
  const int jhalf = bid & 1;
  const int itile = (bid >> 1) & 31;
  const int b = bid >> 6;
  const int i0 = itile * 16;
  const int j0 = jhalf * 256 + lane * 4;

  // all 8 s_dst candidate quads for this thread's 4 j's -> 32 VGPRs
  const float* __restrict__ sdb = s_dstT + (long)b * NN * TT;
  f32x4 sd[TT];
#pragma unroll
  for (int t = 0; t < TT; ++t) sd[t] = *(const f32x4*)(sdb + t * NN + j0);

  // all 4 edge quads up front (rows i0 + it*4 + wave)
  i32x4 e4[4];
#pragma unroll
  for (int it = 0; it < 4; ++it) {
    const long rbase = ((long)(b * NN + i0 + it * 4 + wave)) * NN + j0;
    e4[it] = *(const i32x4*)(edges + rbase);
  }

  // stage 16 rows of s_src (128 floats)
  if (tid < 32) {
    ((f32x4*)ssc)[tid] =
        ((const f32x4*)(s_src + ((long)b * NN + i0) * TT))[tid];
  }
  __syncthreads();

#pragma unroll
  for (int it = 0; it < 4; ++it) {
    const int r = it * 4 + wave;  // wave-uniform local row
    const long rbase = ((long)(b * NN + i0 + r)) * NN + j0;
    const int es[4] = {e4[it].x, e4[it].y, e4[it].z, e4[it].w};
    float oo[4];
#pragma unroll
    for (int m = 0; m < 4; ++m) {
      const int e = es[m];
      const int k = e < 0 ? 0 : e;  // v_max_i32; e>=0 already < T
      // 7-cndmask binary select of sd[k][m]
      const float a0 = (k & 1) ? sd[1][m] : sd[0][m];
      const float a1 = (k & 1) ? sd[3][m] : sd[2][m];
      const float a2 = (k & 1) ? sd[5][m] : sd[4][m];
      const float a3 = (k & 1) ? sd[7][m] : sd[6][m];
      const float b0 = (k & 2) ? a1 : a0;
      const float b1 = (k & 2) ? a3 : a2;
      const float dsel = (k & 4) ? b1 : b0;
      const float g = ssc[r * TT + k] + dsel;
      const float w = fmaxf(g, NEG_SLOPE * g);  // leaky
      oo[m] = e < 0 ? 0.0f : w;                 // edge mask
    }
    const f32x4 o = {oo[0], oo[1], oo[2], oo[3]};
    *(f32x4*)(out + rbase) = o;
  }
}

// ---------------------------------------------------------------------------
extern "C" void kernel_launch(void* const* d_in, const int* in_sizes, int n_in,
                              void* d_out, int out_size, void* d_ws, size_t ws_size,
                              hipStream_t stream) {
  const float* src = (const float*)d_in[0];
  const float* dst = (const float*)d_in[1];
  const int* edges = (const int*)d_in[2];
  const float* a = (const float*)d_in[3];
  float* out = (float*)d_out;

  float* s_src = (float*)d_ws;                       // [B*N, T]   1 MiB
  float* s_dstT = s_src + (long)BB * NN * TT;        // [B, T, N]  1 MiB

  precompute_scores<<<1024, 256, 0, stream>>>(src, dst, a, s_src, s_dstT);

  // 64 b x 32 i-tiles x 2 j-halves = 4096 blocks, 256 threads
  edge_attention<<<BB * 64, 256, 0, stream>>>(edges, s_src, s_dstT, out);
}

// Round 14
// 148.729 us; speedup vs baseline: 1.1132x; 1.0623x over previous
//
#include <hip/hip_runtime.h>

#define BB 64
#define NN 512
#define DD 128
#define TT 8
#define NEG_SLOPE 0.2f

typedef float f32x4 __attribute__((ext_vector_type(4)));
typedef int i32x4 __attribute__((ext_vector_type(4)));

// ---------------------------------------------------------------------------
// Kernel 1: projections — R3 16-lane-per-row version (dup-free loads).
//   s_src [b*N+n][t]          = sum_d src[b,n,d] * a[t*2D + d]
//   s_dstT[b][t][n] (t-major) = sum_d dst[b,n,d] * a[t*2D + D + d]
// 16 lanes/row, 8 d's per lane (each global element read exactly once);
// ar[t][8] in regs amortized over 16 row-instances (2 passes x 2 halves).
// Reduce: xor 1,2,4 over 8-lane groups for all t, select t=sl&7, xor 8.
// ---------------------------------------------------------------------------
__global__ __launch_bounds__(256) void precompute_scores(
    const float* __restrict__ src, const float* __restrict__ dst,
    const float* __restrict__ a, float* __restrict__ s_src,
    float* __restrict__ s_dstT) {
  const int tid = threadIdx.x;
  const int wave = tid >> 6;
  const int lane = tid & 63;
  const int sub = lane >> 4;   // which of 4 rows in this wave
  const int sl = lane & 15;    // 16-lane slice within row
  const int dd0 = sl * 8;      // this lane's d-chunk

#pragma unroll
  for (int half = 0; half < 2; ++half) {
    const float* __restrict__ X = half ? dst : src;
    float ar[TT][8];
#pragma unroll
    for (int t = 0; t < TT; ++t) {
      const f32x4 a0 = *(const f32x4*)(a + t * 2 * DD + half * DD + dd0);
      const f32x4 a1 = *(const f32x4*)(a + t * 2 * DD + half * DD + dd0 + 4);
      ar[t][0] = a0.x; ar[t][1] = a0.y; ar[t][2] = a0.z; ar[t][3] = a0.w;
      ar[t][4] = a1.x; ar[t][5] = a1.y; ar[t][6] = a1.z; ar[t][7] = a1.w;
    }
#pragma unroll
    for (int pass = 0; pass < 2; ++pass) {
      const int r = pass * 16384 + blockIdx.x * 16 + wave * 4 + sub;  // 0..32767
      const f32x4 x0 = *(const f32x4*)(X + (long)r * DD + dd0);
      const f32x4 x1 = *(const f32x4*)(X + (long)r * DD + dd0 + 4);

      float p[TT];
#pragma unroll
      for (int t = 0; t < TT; ++t) {
        p[t] = x0.x * ar[t][0] + x0.y * ar[t][1] + x0.z * ar[t][2] +
               x0.w * ar[t][3] + x1.x * ar[t][4] + x1.y * ar[t][5] +
               x1.z * ar[t][6] + x1.w * ar[t][7];
      }
#pragma unroll
      for (int t = 0; t < TT; ++t) {
        p[t] += __shfl_xor(p[t], 1, 64);
        p[t] += __shfl_xor(p[t], 2, 64);
        p[t] += __shfl_xor(p[t], 4, 64);
      }
      const int tk = sl & 7;
      float v = p[0];
      v = tk == 1 ? p[1] : v;
      v = tk == 2 ? p[2] : v;
      v = tk == 3 ? p[3] : v;
      v = tk == 4 ? p[4] : v;
      v = tk == 5 ? p[5] : v;
      v = tk == 6 ? p[6] : v;
      v = tk == 7 ? p[7] : v;
      v += __shfl_xor(v, 8, 64);

      if (sl < 8) {
        if (half == 0) {
          s_src[(long)r * TT + sl] = v;  // contiguous per wave
        } else {
          const int b = r >> 9, n = r & 511;
          s_dstT[((long)b * TT + sl) * NN + n] = v;  // [b][t][n]
        }
      }
    }
  }
}

// ---------------------------------------------------------------------------
// Kernel 2 (register-select, unchanged from R13):
//   out[b,i,j] = leakyrelu( (e>=0) ? s_src[b,i,e] + s_dst[b,j,e] : 0 )
// Block = 256 threads (b, 16-row i-tile, 256-wide j-half); 4096 blocks.
// Thread holds s_dstT[b][t][j0..j0+3] for ALL t in 32 VGPRs; gather =
// 7-cndmask tree. 512 B LDS, plain f32x4 stores.
// ---------------------------------------------------------------------------
__global__ __launch_bounds__(256) void edge_attention(
    const int* __restrict__ edges, const float* __restrict__ s_src,
    const float* __restrict__ s_dstT, float* __restrict__ out) {
  __shared__ float ssc[16 * TT];  // [local row][t] 512 B

  const int tid = threadIdx.x;
  const int wave = tid >> 6, lane = tid & 63;
  const int bid = blockIdx.x;
  const int jhalf = bid & 1;
  const int itile = (bid >> 1) & 31;
  const int b = bid >> 6;
  const int i0 = itile * 16;
  const int j0 = jhalf * 256 + lane * 4;

  const float* __restrict__ sdb = s_dstT + (long)b * NN * TT;
  f32x4 sd[TT];
#pragma unroll
  for (int t = 0; t < TT; ++t) sd[t] = *(const f32x4*)(sdb + t * NN + j0);

  i32x4 e4[4];
#pragma unroll
  for (int it = 0; it < 4; ++it) {
    const long rbase = ((long)(b * NN + i0 + it * 4 + wave)) * NN + j0;
    e4[it] = *(const i32x4*)(edges + rbase);
  }

  if (tid < 32) {
    ((f32x4*)ssc)[tid] =
        ((const f32x4*)(s_src + ((long)b * NN + i0) * TT))[tid];
  }
  __syncthreads();

#pragma unroll
  for (int it = 0; it < 4; ++it) {
    const int r = it * 4 + wave;  // wave-uniform local row
    const long rbase = ((long)(b * NN + i0 + r)) * NN + j0;
    const int es[4] = {e4[it].x, e4[it].y, e4[it].z, e4[it].w};
    float oo[4];
#pragma unroll
    for (int m = 0; m < 4; ++m) {
      const int e = es[m];
      const int k = e < 0 ? 0 : e;  // v_max_i32; e>=0 already < T
      const float a0 = (k & 1) ? sd[1][m] : sd[0][m];
      const float a1 = (k & 1) ? sd[3][m] : sd[2][m];
      const float a2 = (k & 1) ? sd[5][m] : sd[4][m];
      const float a3 = (k & 1) ? sd[7][m] : sd[6][m];
      const float b0 = (k & 2) ? a1 : a0;
      const float b1 = (k & 2) ? a3 : a2;
      const float dsel = (k & 4) ? b1 : b0;
      const float g = ssc[r * TT + k] + dsel;
      const float w = fmaxf(g, NEG_SLOPE * g);  // leaky
      oo[m] = e < 0 ? 0.0f : w;                 // edge mask
    }
    const f32x4 o = {oo[0], oo[1], oo[2], oo[3]};
    *(f32x4*)(out + rbase) = o;
  }
}

// ---------------------------------------------------------------------------
extern "C" void kernel_launch(void* const* d_in, const int* in_sizes, int n_in,
                              void* d_out, int out_size, void* d_ws, size_t ws_size,
                              hipStream_t stream) {
  const float* src = (const float*)d_in[0];
  const float* dst = (const float*)d_in[1];
  const int* edges = (const int*)d_in[2];
  const float* a = (const float*)d_in[3];
  float* out = (float*)d_out;

  float* s_src = (float*)d_ws;                       // [B*N, T]   1 MiB
  float* s_dstT = s_src + (long)BB * NN * TT;        // [B, T, N]  1 MiB

  // Kernel 1: 16 rows/block-pass, 2 passes, 2 halves -> 1024 blocks
  precompute_scores<<<1024, 256, 0, stream>>>(src, dst, a, s_src, s_dstT);

  // Kernel 2: 64 b x 32 i-tiles x 2 j-halves = 4096 blocks, 256 threads
  edge_attention<<<BB * 64, 256, 0, stream>>>(edges, s_src, s_dstT, out);
}